// Round 9
// baseline (154.137 us; speedup 1.0000x reference)
//
#include <hip/hip_runtime.h>

// Problem collapses: output = classifier(node 0) only.
//   out = dot(wc, mean(pool(lrelu(conv3(p2)+b3)))) + bc
//   p2  = pool(lrelu(conv2(12*P1) + 4*b2))   (node 1, indeg=4)
//   P1  = pool(lrelu(conv1(x)+b1))           (sum indegs over {0,2,4,6} = 12)
//
// R22: occupancy attack, correctness-fixed. R20/R21's absmax 24.5 was a
// readfirstlane on a LANE-DIVERGENT cin (grp depended on l>>5): upper lane
// halves used the lower half's weights. Fix: cin split is by wave ONLY
// (cin = wvs*8+cl, uniform); each lane owns one spatial position
// (col l&31, row l>>5). Scalar FMA (chip-wide FLOPs unchanged; R18 showed
// pk vs scalar neutral). k3 de-packed for VGPR headroom at the 64-reg cap.
// k2/k3: 2048 blocks = 8 blocks/CU, 8 waves/SIMD (launch_bounds(256,8)).

#define LRELU(v) fmaxf((v), 0.2f * (v))

#define P1H_ELEMS (32 * 32 * 34 * 36)
#define P2H_ELEMS (32 * 64 * 18 * 20)

typedef float vf2 __attribute__((ext_vector_type(2)));

// ---------- k1: conv1 4->32 @64x64, +b1, lrelu, pool2, *12 -> P1H ----------
__global__ __launch_bounds__(256, 4) void k1(const float* __restrict__ x,
                                             const float* __restrict__ w1,
                                             const float* __restrict__ b1,
                                             float* __restrict__ P1H,
                                             float* __restrict__ out) {
    __shared__ __align__(16) float obuf[1152];     // [4co][8prow][36]
    const int bx = blockIdx.x;                     // 32 = rb(4) x cog(8)
    const int b  = blockIdx.y;
    const int rb = bx & 3, cog = bx >> 2;
    const int t  = threadIdx.x;
    const int l = t & 63, wv = t >> 6;
    const int r = l >> 4, q = l & 15;
    const int row0 = 16 * rb + 4 * wv + r;         // pre-pool row 0..63

    if (bx == 0 && t == 0) out[b] = 0.f;           // k3 atomics ordered after

    for (int i = t; i < 288; i += 256)
        *(float4*)&obuf[4 * i] = make_float4(0.f, 0.f, 0.f, 0.f);
    __syncthreads();

    const bool cL = (q > 0), cR = (q < 15);
    const int colL = max(4 * q - 2, 0);
    const int colR = min(4 * q + 4, 62);

    vf2 acc[4][2];
    #pragma unroll
    for (int g = 0; g < 4; ++g) {
        float bias = b1[cog * 4 + g];
        acc[g][0] = (vf2){bias, bias};
        acc[g][1] = (vf2){bias, bias};
    }

    #pragma unroll
    for (int c = 0; c < 4; ++c) {
        float win[3][6];
        #pragma unroll
        for (int d = 0; d < 3; ++d) {
            int gr = row0 - 1 + d;
            bool v = (unsigned)gr < 64u;
            int grc = min(max(gr, 0), 63);
            const float* row = x + ((b * 4 + c) * 64 + grc) * 64;
            float2 L  = *(const float2*)(row + colL);
            float4 M  = *(const float4*)(row + 4 * q);
            float2 R2 = *(const float2*)(row + colR);
            win[d][0] = (v && cL) ? L.y : 0.f;
            win[d][1] = v ? M.x : 0.f;
            win[d][2] = v ? M.y : 0.f;
            win[d][3] = v ? M.z : 0.f;
            win[d][4] = v ? M.w : 0.f;
            win[d][5] = (v && cR) ? R2.x : 0.f;
        }
        vf2 wp[3][5];                              // shifted col pairs, reused /co
        #pragma unroll
        for (int d = 0; d < 3; ++d)
            #pragma unroll
            for (int k = 0; k < 5; ++k)
                wp[d][k] = (vf2){win[d][k], win[d][k + 1]};
        #pragma unroll
        for (int g = 0; g < 4; ++g) {
            const float* wpt = &w1[((cog * 4 + g) * 4 + c) * 9];  // tiny K$ set
            #pragma unroll
            for (int d = 0; d < 3; ++d)
                #pragma unroll
                for (int j = 0; j < 3; ++j) {
                    float w = wpt[3 * d + j];
                    acc[g][0] += w * wp[d][j];      // v_pk_fma_f32
                    acc[g][1] += w * wp[d][j + 2];
                }
        }
    }

    const int prow_l = 2 * wv + (r >> 1);
    #pragma unroll
    for (int g = 0; g < 4; ++g) {
        float m0 = fmaxf(LRELU(acc[g][0].x), LRELU(acc[g][0].y));
        float m1 = fmaxf(LRELU(acc[g][1].x), LRELU(acc[g][1].y));
        float p0 = fmaxf(m0, __shfl_xor(m0, 16));
        float p1 = fmaxf(m1, __shfl_xor(m1, 16));
        if ((r & 1) == 0) {
            obuf[(g * 8 + prow_l) * 36 + 2 * q + 1] = 12.f * p0;
            obuf[(g * 8 + prow_l) * 36 + 2 * q + 2] = 12.f * p1;
        }
    }
    __syncthreads();

    for (int i = t; i < 288; i += 256) {
        int co_l = i / 72, rem = i % 72, pr = rem / 9, cw = rem % 9;
        *(float4*)&P1H[((b * 32 + cog * 4 + co_l) * 34 + 8 * rb + pr + 1) * 36 + 4 * cw] =
            *(const float4*)&obuf[4 * i];
    }
    if (rb == 0 || rb == 3) {
        int h = rb ? 33 : 0;
        for (int i = t; i < 36; i += 256) {
            int co_l = i / 9, cw = i % 9;
            *(float4*)&P1H[((b * 32 + cog * 4 + co_l) * 34 + h) * 36 + 4 * cw] =
                make_float4(0.f, 0.f, 0.f, 0.f);
        }
    }
}

// ---------- k2: conv2 32->64 @32x32, +4*b2, lrelu, pool2 -> p2H ------------
// grid.x = 64 = cog(4) x rs(16); block = 16 co x 1 out-row x 16 out-cols.
// Lane owns one spatial position: pre-col c=l&31, pre-row 2rs+(l>>5).
// Waves split cin 4x8 (WAVE-UNIFORM cin -> legal readfirstlane s_loads).
// Cross-wave combine via LDS; pool via shfl_xor(1) + shfl_xor(32).
__global__ __launch_bounds__(256, 8) void k2(const float* __restrict__ P1H,
                                             const float* __restrict__ w2,
                                             const float* __restrict__ b2,
                                             float* __restrict__ p2H) {
    __shared__ __align__(16) float xin[4608];   // [32cin][4r][36]; cbuf [3][64][20]
    __shared__ __align__(16) float obuf[320];   // [16co][20]
    const int bx = blockIdx.x;                  // 64 = cog(4) x rs(16)
    const int b  = blockIdx.y;
    const int cog = bx >> 4, rs = bx & 15;
    const int c0  = cog * 16;
    const int t = threadIdx.x, l = t & 63;
    const int wvs = __builtin_amdgcn_readfirstlane(t >> 6);
    const int c  = l & 31;                      // pre-col; haloed window c..c+2
    const int rw = l >> 5;                      // pre-row 2rs+rw

    // stage 32 cin x 4 haloed rows (rs*2 .. rs*2+3)
    for (int i = t; i < 1152; i += 256) {
        int cin = i / 36, rem = i % 36, r = rem / 9, cw = rem % 9;
        *(float4*)&xin[cin * 144 + r * 36 + 4 * cw] =
            *(const float4*)&P1H[((b * 32 + cin) * 34 + rs * 2 + r) * 36 + 4 * cw];
    }
    for (int i = t; i < 80; i += 256)
        *(float4*)&obuf[4 * i] = make_float4(0.f, 0.f, 0.f, 0.f);
    __syncthreads();

    float acc[16];
    #pragma unroll
    for (int co = 0; co < 16; ++co)
        acc[co] = (wvs == 0) ? 4.f * b2[c0 + co] : 0.f;

    #pragma unroll 2
    for (int cl = 0; cl < 8; ++cl) {
        const int cin = wvs * 8 + cl;           // wave-uniform
        float win[3][3];
        #pragma unroll
        for (int d = 0; d < 3; ++d) {
            const float* xr = &xin[cin * 144 + (rw + d) * 36 + c];
            win[d][0] = xr[0]; win[d][1] = xr[1]; win[d][2] = xr[2];
        }
        // wave-uniform weight base -> s_load into SGPRs
        const int wbase = __builtin_amdgcn_readfirstlane((c0 * 32 + cin) * 9);
        #pragma unroll
        for (int co = 0; co < 16; ++co) {
            const float* wg = w2 + wbase + co * 288;   // += (co*32cin)*9
            float wt[9];
            #pragma unroll
            for (int k = 0; k < 9; ++k) wt[k] = wg[k];
            #pragma unroll
            for (int d = 0; d < 3; ++d)
                #pragma unroll
                for (int j = 0; j < 3; ++j)
                    acc[co] += wt[3 * d + j] * win[d][j];
        }
    }

    __syncthreads();                 // xin reads done -> reuse as cbuf (stride 20)
    if (wvs > 0) {
        float* cb = &xin[((wvs - 1) * 64 + l) * 20];
        #pragma unroll
        for (int g = 0; g < 4; ++g)
            *(float4*)&cb[4 * g] = make_float4(acc[4 * g], acc[4 * g + 1],
                                               acc[4 * g + 2], acc[4 * g + 3]);
    }
    __syncthreads();
    if (wvs == 0) {
        #pragma unroll
        for (int k = 0; k < 3; ++k) {
            const float* cb = &xin[(k * 64 + l) * 20];
            #pragma unroll
            for (int g = 0; g < 4; ++g) {
                float4 v = *(const float4*)&cb[4 * g];
                acc[4 * g]     += v.x; acc[4 * g + 1] += v.y;
                acc[4 * g + 2] += v.z; acc[4 * g + 3] += v.w;
            }
        }
        // pool: col pair via shfl_xor(1); row pair via shfl_xor(32)
        #pragma unroll
        for (int co = 0; co < 16; ++co) {
            float a  = LRELU(acc[co]);
            float p1 = fmaxf(a, __shfl_xor(a, 1));
            float p  = fmaxf(p1, __shfl_xor(p1, 32));
            if (rw == 0 && (c & 1) == 0)
                obuf[co * 20 + (c >> 1) + 1] = p;
        }
    }
    __syncthreads();

    // full-line coalesced stores (80 B rows incl. halo cols)
    for (int i = t; i < 80; i += 256) {
        int co = i / 5, cw = i % 5;
        *(float4*)&p2H[((b * 64 + c0 + co) * 18 + rs + 1) * 20 + 4 * cw] =
            *(const float4*)&obuf[4 * i];
    }
    if (rs == 0 || rs == 15) {
        int h2 = rs ? 17 : 0;
        for (int i = t; i < 80; i += 256) {
            int co = i / 5, cw = i % 5;
            *(float4*)&p2H[((b * 64 + c0 + co) * 18 + h2) * 20 + 4 * cw] =
                make_float4(0.f, 0.f, 0.f, 0.f);
        }
    }
}

// ---------- k3: conv3 64->128 @16x16, +b3, lrelu, pool2, mean, dot ---------
// block = 2-co group (64 of them, 2048 blocks = 8/CU); waves split cin
// (cin = ch*8 + wvs*2 + cl, wave-uniform). p2H staged in 8 chunks of 8 cin.
// Scalar FMA (VGPR headroom at the 64-reg cap). Combine stride 20.
__global__ __launch_bounds__(256, 8) void k3(const float* __restrict__ p2H,
                                             const float* __restrict__ w3,
                                             const float* __restrict__ b3,
                                             const float* __restrict__ wc,
                                             const float* __restrict__ bc,
                                             float* __restrict__ out) {
    __shared__ __align__(16) float xs[3840];     // [8cin][18][20]; cbuf [3][64][20]
    const int cog = blockIdx.x;                  // 0..63 -> 2 co
    const int b   = blockIdx.y;
    const int c0  = cog * 2;
    const int t   = threadIdx.x, l = t & 63;
    const int wvs = __builtin_amdgcn_readfirstlane(t >> 6);
    const int r   = l >> 2, q = l & 3;

    float acc[2][4];
    #pragma unroll
    for (int g = 0; g < 2; ++g) {
        float bias = (wvs == 0) ? b3[c0 + g] : 0.f;
        acc[g][0] = bias; acc[g][1] = bias; acc[g][2] = bias; acc[g][3] = bias;
    }

    for (int ch = 0; ch < 8; ++ch) {
        if (ch) __syncthreads();                 // prev chunk reads done
        for (int i = t; i < 720; i += 256) {     // 8cin x 18r x 20c / 4
            int cin_l = i / 90, rem = i % 90;
            *(float4*)&xs[cin_l * 360 + 4 * rem] =
                *(const float4*)&p2H[(b * 64 + ch * 8 + cin_l) * 360 + 4 * rem];
        }
        __syncthreads();
        #pragma unroll
        for (int cl = 0; cl < 2; ++cl) {
            const int cin_l = wvs * 2 + cl;      // staged index (wave splits 8)
            const int cin   = ch * 8 + cin_l;    // wave-uniform
            const float* pb = &xs[cin_l * 360 + r * 20 + 4 * q];
            float win[3][6];
            #pragma unroll
            for (int d = 0; d < 3; ++d) {
                float4 M  = *(const float4*)(pb + d * 20);
                float2 Rt = *(const float2*)(pb + d * 20 + 4);
                win[d][0] = M.x; win[d][1] = M.y; win[d][2] = M.z;
                win[d][3] = M.w; win[d][4] = Rt.x; win[d][5] = Rt.y;
            }
            const int wbase = __builtin_amdgcn_readfirstlane((c0 * 64 + cin) * 9);
            #pragma unroll
            for (int g = 0; g < 2; ++g) {
                const float* wg = w3 + wbase + g * 576;   // += (g*64cin)*9
                float wt[9];
                #pragma unroll
                for (int k = 0; k < 9; ++k) wt[k] = wg[k];
                #pragma unroll
                for (int d = 0; d < 3; ++d)
                    #pragma unroll
                    for (int j = 0; j < 3; ++j) {
                        float w = wt[3 * d + j];
                        acc[g][0] += w * win[d][j];
                        acc[g][1] += w * win[d][j + 1];
                        acc[g][2] += w * win[d][j + 2];
                        acc[g][3] += w * win[d][j + 3];
                    }
            }
        }
    }

    __syncthreads();   // xs reads done -> reuse as cbuf (stride 20)
    if (wvs > 0) {
        float* cb = &xs[((wvs - 1) * 64 + l) * 20];
        #pragma unroll
        for (int g = 0; g < 2; ++g)
            *(float4*)&cb[4 * g] =
                make_float4(acc[g][0], acc[g][1], acc[g][2], acc[g][3]);
    }
    __syncthreads();

    if (wvs == 0) {
        #pragma unroll
        for (int k = 0; k < 3; ++k) {
            const float* cb = &xs[(k * 64 + l) * 20];
            #pragma unroll
            for (int g = 0; g < 2; ++g) {
                float4 v = *(const float4*)&cb[4 * g];
                acc[g][0] += v.x; acc[g][1] += v.y;
                acc[g][2] += v.z; acc[g][3] += v.w;
            }
        }
        float vsum = 0.f;
        #pragma unroll
        for (int g = 0; g < 2; ++g) {
            float m0 = fmaxf(LRELU(acc[g][0]), LRELU(acc[g][1]));
            float m1 = fmaxf(LRELU(acc[g][2]), LRELU(acc[g][3]));
            float pm0 = fmaxf(m0, __shfl_xor(m0, 4));
            float pm1 = fmaxf(m1, __shfl_xor(m1, 4));
            float contrib = ((r & 1) == 0) ? (pm0 + pm1) : 0.f;
            vsum += contrib * wc[c0 + g];
        }
        #pragma unroll
        for (int off = 32; off > 0; off >>= 1) vsum += __shfl_xor(vsum, off);
        if (l == 0) {
            float o = vsum * (1.f / 64.f);
            if (cog == 0) o += bc[0];
            atomicAdd(&out[b], o);
        }
    }
}

extern "C" void kernel_launch(void* const* d_in, const int* in_sizes, int n_in,
                              void* d_out, int out_size, void* d_ws, size_t ws_size,
                              hipStream_t stream) {
    const float* x  = (const float*)d_in[0];
    const float* w1 = (const float*)d_in[1];
    const float* b1 = (const float*)d_in[2];
    const float* w2 = (const float*)d_in[3];
    const float* b2 = (const float*)d_in[4];
    const float* w3 = (const float*)d_in[5];
    const float* b3 = (const float*)d_in[6];
    const float* wc = (const float*)d_in[7];
    const float* bc = (const float*)d_in[8];
    float* out = (float*)d_out;

    float* P1H = (float*)d_ws;                    // [32][32][34][36] ~5.4 MB
    float* p2H = P1H + P1H_ELEMS;                 // [32][64][18][20] ~2.8 MB

    k1<<<dim3(32, 32), 256, 0, stream>>>(x, w1, b1, P1H, out);
    k2<<<dim3(64, 32), 256, 0, stream>>>(P1H, w2, b2, p2H);
    k3<<<dim3(64, 32), 256, 0, stream>>>(p2H, w3, b3, wc, bc, out);
}

// Round 10
// 130.111 us; speedup vs baseline: 1.1847x; 1.1847x over previous
//
#include <hip/hip_runtime.h>

// Problem collapses: output = classifier(node 0) only.
//   out = dot(wc, mean(pool(lrelu(conv3(p2)+b3)))) + bc
//   p2  = pool(lrelu(conv2(12*P1) + 4*b2))   (node 1, indeg=4)
//   P1  = pool(lrelu(conv1(x)+b1))           (sum indegs over {0,2,4,6} = 12)
//
// R23 = R18 base (best known, 131.18) + k3 LDS bank-conflict fix.
// R22 counters (k3@2co: 48us, VALU 28%, LDS_BANK_CONFLICT 11.3M cyc) showed
// k3's window ds_read_b128 at stride 20 floats serializes 1.5x per 16-lane
// phase (starts (20r+4q)%32 hit spans 3/2/1x). Stride 24: starts
// {0,24,16,8}+{0,4,8,12} tile every 4-bank span exactly 2x = free (m136).
// xs: [16cin][18][24] = 27.6 KB; combine buf stays stride 20 (already 2x).
// Occupancy axis falsified (R22: 2x blocks = 2x staging = slower); back to
// 1024 blocks / 4 co. k1/k2 identical to R18.

#define LRELU(v) fmaxf((v), 0.2f * (v))

#define P1H_ELEMS (32 * 32 * 34 * 36)
#define P2H_ELEMS (32 * 64 * 18 * 20)

typedef float vf2 __attribute__((ext_vector_type(2)));

// ---------- k1: conv1 4->32 @64x64, +b1, lrelu, pool2, *12 -> P1H ----------
__global__ __launch_bounds__(256, 4) void k1(const float* __restrict__ x,
                                             const float* __restrict__ w1,
                                             const float* __restrict__ b1,
                                             float* __restrict__ P1H,
                                             float* __restrict__ out) {
    __shared__ __align__(16) float obuf[1152];     // [4co][8prow][36]
    const int bx = blockIdx.x;                     // 32 = rb(4) x cog(8)
    const int b  = blockIdx.y;
    const int rb = bx & 3, cog = bx >> 2;
    const int t  = threadIdx.x;
    const int l = t & 63, wv = t >> 6;
    const int r = l >> 4, q = l & 15;
    const int row0 = 16 * rb + 4 * wv + r;         // pre-pool row 0..63

    if (bx == 0 && t == 0) out[b] = 0.f;           // k3 atomics ordered after

    for (int i = t; i < 288; i += 256)
        *(float4*)&obuf[4 * i] = make_float4(0.f, 0.f, 0.f, 0.f);
    __syncthreads();

    const bool cL = (q > 0), cR = (q < 15);
    const int colL = max(4 * q - 2, 0);
    const int colR = min(4 * q + 4, 62);

    vf2 acc[4][2];
    #pragma unroll
    for (int g = 0; g < 4; ++g) {
        float bias = b1[cog * 4 + g];
        acc[g][0] = (vf2){bias, bias};
        acc[g][1] = (vf2){bias, bias};
    }

    #pragma unroll
    for (int c = 0; c < 4; ++c) {
        float win[3][6];
        #pragma unroll
        for (int d = 0; d < 3; ++d) {
            int gr = row0 - 1 + d;
            bool v = (unsigned)gr < 64u;
            int grc = min(max(gr, 0), 63);
            const float* row = x + ((b * 4 + c) * 64 + grc) * 64;
            float2 L  = *(const float2*)(row + colL);
            float4 M  = *(const float4*)(row + 4 * q);
            float2 R2 = *(const float2*)(row + colR);
            win[d][0] = (v && cL) ? L.y : 0.f;
            win[d][1] = v ? M.x : 0.f;
            win[d][2] = v ? M.y : 0.f;
            win[d][3] = v ? M.z : 0.f;
            win[d][4] = v ? M.w : 0.f;
            win[d][5] = (v && cR) ? R2.x : 0.f;
        }
        vf2 wp[3][5];                              // shifted col pairs, reused /co
        #pragma unroll
        for (int d = 0; d < 3; ++d)
            #pragma unroll
            for (int k = 0; k < 5; ++k)
                wp[d][k] = (vf2){win[d][k], win[d][k + 1]};
        #pragma unroll
        for (int g = 0; g < 4; ++g) {
            const float* wpt = &w1[((cog * 4 + g) * 4 + c) * 9];  // tiny K$ set
            #pragma unroll
            for (int d = 0; d < 3; ++d)
                #pragma unroll
                for (int j = 0; j < 3; ++j) {
                    float w = wpt[3 * d + j];
                    acc[g][0] += w * wp[d][j];      // v_pk_fma_f32
                    acc[g][1] += w * wp[d][j + 2];
                }
        }
    }

    const int prow_l = 2 * wv + (r >> 1);
    #pragma unroll
    for (int g = 0; g < 4; ++g) {
        float m0 = fmaxf(LRELU(acc[g][0].x), LRELU(acc[g][0].y));
        float m1 = fmaxf(LRELU(acc[g][1].x), LRELU(acc[g][1].y));
        float p0 = fmaxf(m0, __shfl_xor(m0, 16));
        float p1 = fmaxf(m1, __shfl_xor(m1, 16));
        if ((r & 1) == 0) {
            obuf[(g * 8 + prow_l) * 36 + 2 * q + 1] = 12.f * p0;
            obuf[(g * 8 + prow_l) * 36 + 2 * q + 2] = 12.f * p1;
        }
    }
    __syncthreads();

    for (int i = t; i < 288; i += 256) {
        int co_l = i / 72, rem = i % 72, pr = rem / 9, cw = rem % 9;
        *(float4*)&P1H[((b * 32 + cog * 4 + co_l) * 34 + 8 * rb + pr + 1) * 36 + 4 * cw] =
            *(const float4*)&obuf[4 * i];
    }
    if (rb == 0 || rb == 3) {
        int h = rb ? 33 : 0;
        for (int i = t; i < 36; i += 256) {
            int co_l = i / 9, cw = i % 9;
            *(float4*)&P1H[((b * 32 + cog * 4 + co_l) * 34 + h) * 36 + 4 * cw] =
                make_float4(0.f, 0.f, 0.f, 0.f);
        }
    }
}

// ---------- k2: conv2 32->64 @32x32, +4*b2, lrelu, pool2 -> p2H ------------
// grid.x = 32 = cog(4) x rs(8); block covers 16 co x 4 pre-rows x 32 cols.
// Waves split cin (8 each), combine via LDS. Weights: scalar loads (SGPR).
// Window b64 reads are conflict-free (starts 2*ql tile all 32 banks).
__global__ __launch_bounds__(256, 4) void k2(const float* __restrict__ P1H,
                                             const float* __restrict__ w2,
                                             const float* __restrict__ b2,
                                             float* __restrict__ p2H) {
    __shared__ __align__(16) float xin[6912];   // [32cin][6r][36]; reused as cbuf [3][64][36]
    __shared__ __align__(16) float obuf[640];   // [16co][2pr][20]
    const int bx = blockIdx.x;                  // 32 = cog(4) x rs(8)
    const int b  = blockIdx.y;
    const int cog = bx >> 3, rs = bx & 7;
    const int c0  = cog * 16;
    const int t = threadIdx.x, l = t & 63;
    const int wvs = __builtin_amdgcn_readfirstlane(t >> 6);
    const int ql = l & 15, R = l >> 4;          // out cols 2ql..2ql+1 ; pre-row rs*4+R

    // stage all 32 cin x 6 rows (rs*4 .. rs*4+5 in haloed P1H coords)
    for (int i = t; i < 1728; i += 256) {
        int cin = i / 54, rem = i % 54, r = rem / 9, cw = rem % 9;
        *(float4*)&xin[cin * 216 + r * 36 + 4 * cw] =
            *(const float4*)&P1H[((b * 32 + cin) * 34 + rs * 4 + r) * 36 + 4 * cw];
    }
    for (int i = t; i < 160; i += 256)
        *(float4*)&obuf[4 * i] = make_float4(0.f, 0.f, 0.f, 0.f);
    __syncthreads();

    vf2 acc[16];
    #pragma unroll
    for (int co = 0; co < 16; ++co) {
        float bias = (wvs == 0) ? 4.f * b2[c0 + co] : 0.f;
        acc[co] = (vf2){bias, bias};
    }

    #pragma unroll 2
    for (int cl = 0; cl < 8; ++cl) {
        const int cin = wvs * 8 + cl;
        float win[3][4];
        #pragma unroll
        for (int d = 0; d < 3; ++d) {
            const float* xr = &xin[cin * 216 + (R + d) * 36 + 2 * ql];
            float2 a0 = *(const float2*)xr;
            float2 a1 = *(const float2*)(xr + 2);
            win[d][0] = a0.x; win[d][1] = a0.y; win[d][2] = a1.x; win[d][3] = a1.y;
        }
        vf2 wp[3][3];                            // col pairs, reused across 16 co
        #pragma unroll
        for (int d = 0; d < 3; ++d)
            #pragma unroll
            for (int k = 0; k < 3; ++k)
                wp[d][k] = (vf2){win[d][k], win[d][k + 1]};
        // wave-uniform weight base -> s_load into SGPRs (no LDS, no VALU)
        const int wbase = __builtin_amdgcn_readfirstlane((c0 * 32 + cin) * 9);
        #pragma unroll
        for (int co = 0; co < 16; ++co) {
            const float* wg = w2 + wbase + co * 288;   // += (co*32cin)*9
            float wt[9];
            #pragma unroll
            for (int k = 0; k < 9; ++k) wt[k] = wg[k];
            #pragma unroll
            for (int d = 0; d < 3; ++d)
                #pragma unroll
                for (int j = 0; j < 3; ++j)
                    acc[co] += wt[3 * d + j] * wp[d][j];   // v_pk_fma_f32
        }
    }

    __syncthreads();                 // xin reads done -> reuse as cbuf (stride 36)
    if (wvs > 0) {
        float* cb = &xin[((wvs - 1) * 64 + l) * 36];
        #pragma unroll
        for (int g = 0; g < 8; ++g)
            *(float4*)&cb[4 * g] = make_float4(acc[2 * g].x, acc[2 * g].y,
                                               acc[2 * g + 1].x, acc[2 * g + 1].y);
    }
    __syncthreads();
    if (wvs == 0) {
        #pragma unroll
        for (int k = 0; k < 3; ++k) {
            const float* cb = &xin[(k * 64 + l) * 36];
            #pragma unroll
            for (int g = 0; g < 8; ++g) {
                float4 v = *(const float4*)&cb[4 * g];
                acc[2 * g].x += v.x;     acc[2 * g].y += v.y;
                acc[2 * g + 1].x += v.z; acc[2 * g + 1].y += v.w;
            }
        }
        // pool: col pair in-lane; row pair via shfl_xor(16) (R <-> R^1)
        #pragma unroll
        for (int co = 0; co < 16; ++co) {
            float m = fmaxf(LRELU(acc[co].x), LRELU(acc[co].y));
            float p = fmaxf(m, __shfl_xor(m, 16));
            if ((R & 1) == 0)
                obuf[(co * 2 + (R >> 1)) * 20 + ql + 1] = p;
        }
    }
    __syncthreads();

    // full-line coalesced stores (80 B rows incl. halo cols)
    for (int i = t; i < 160; i += 256) {
        int co = i / 10, rem = i % 10, pr = rem / 5, cw = rem % 5;
        *(float4*)&p2H[((b * 64 + c0 + co) * 18 + rs * 2 + 1 + pr) * 20 + 4 * cw] =
            *(const float4*)&obuf[4 * i];
    }
    if (rs == 0 || rs == 7) {
        int h2 = rs ? 17 : 0;
        for (int i = t; i < 80; i += 256) {
            int co = i / 5, cw = i % 5;
            *(float4*)&p2H[((b * 64 + c0 + co) * 18 + h2) * 20 + 4 * cw] =
                make_float4(0.f, 0.f, 0.f, 0.f);
        }
    }
}

// ---------- k3: conv3 64->128 @16x16, +b3, lrelu, pool2, mean, dot ---------
// block = 4-co group (32 of them, 1024 blocks = 4/CU); waves split cin.
// p2H staged in LDS in 4 chunks of 16 cin at PADDED stride 24 floats
// ([16][18][24] = 27.6 KB): window b128 starts (24r+4q)%32 tile every
// 4-bank span exactly 2x per 16-lane phase = conflict-free. Weights via
// wave-uniform scalar loads. Combine buf stride 20 (already 2x-tiled).
__global__ __launch_bounds__(256, 4) void k3(const float* __restrict__ p2H,
                                             const float* __restrict__ w3,
                                             const float* __restrict__ b3,
                                             const float* __restrict__ wc,
                                             const float* __restrict__ bc,
                                             float* __restrict__ out) {
    __shared__ __align__(16) float xs[6912];     // [16cin][18][24]; cbuf [3][64][20]
    const int cog = blockIdx.x;                  // 0..31 -> 4 co
    const int b   = blockIdx.y;
    const int c0  = cog * 4;
    const int t   = threadIdx.x, l = t & 63;
    const int wvs = __builtin_amdgcn_readfirstlane(t >> 6);
    const int r   = l >> 2, q = l & 3;

    vf2 acc[4][2];
    #pragma unroll
    for (int g = 0; g < 4; ++g) {
        float bias = (wvs == 0) ? b3[c0 + g] : 0.f;
        acc[g][0] = (vf2){bias, bias};
        acc[g][1] = (vf2){bias, bias};
    }

    for (int ch = 0; ch < 4; ++ch) {
        if (ch) __syncthreads();                 // prev chunk reads done
        for (int i = t; i < 1440; i += 256) {    // 16cin x 18r x 5 float4
            int cin_l = i / 90, rem = i % 90;
            int rr = rem / 5, c4 = rem % 5;
            *(float4*)&xs[cin_l * 432 + rr * 24 + 4 * c4] =
                *(const float4*)&p2H[(b * 64 + ch * 16 + cin_l) * 360 + 4 * rem];
        }
        __syncthreads();
        #pragma unroll
        for (int cl = 0; cl < 4; ++cl) {
            const int cin_l = wvs * 4 + cl;      // staged index (wave splits 16)
            const int cin   = ch * 16 + cin_l;
            const float* pb = &xs[cin_l * 432 + r * 24 + 4 * q];
            float win[3][6];
            #pragma unroll
            for (int d = 0; d < 3; ++d) {
                float4 M  = *(const float4*)(pb + d * 24);
                float2 Rt = *(const float2*)(pb + d * 24 + 4);
                win[d][0] = M.x; win[d][1] = M.y; win[d][2] = M.z;
                win[d][3] = M.w; win[d][4] = Rt.x; win[d][5] = Rt.y;
            }
            vf2 wp[3][5];                        // shifted col pairs, reused /co
            #pragma unroll
            for (int d = 0; d < 3; ++d)
                #pragma unroll
                for (int k = 0; k < 5; ++k)
                    wp[d][k] = (vf2){win[d][k], win[d][k + 1]};
            const int wbase = __builtin_amdgcn_readfirstlane((c0 * 64 + cin) * 9);
            #pragma unroll
            for (int g = 0; g < 4; ++g) {
                const float* wg = w3 + wbase + g * 576;   // += (g*64cin)*9
                float wt[9];
                #pragma unroll
                for (int k = 0; k < 9; ++k) wt[k] = wg[k];
                #pragma unroll
                for (int d = 0; d < 3; ++d)
                    #pragma unroll
                    for (int j = 0; j < 3; ++j) {
                        float w = wt[3 * d + j];
                        acc[g][0] += w * wp[d][j];      // v_pk_fma_f32
                        acc[g][1] += w * wp[d][j + 2];
                    }
            }
        }
    }

    __syncthreads();   // xs reads done -> reuse as cbuf (stride 20)
    if (wvs > 0) {
        float* cb = &xs[((wvs - 1) * 64 + l) * 20];
        #pragma unroll
        for (int g = 0; g < 4; ++g)
            *(float4*)&cb[4 * g] =
                make_float4(acc[g][0].x, acc[g][0].y, acc[g][1].x, acc[g][1].y);
    }
    __syncthreads();

    if (wvs == 0) {
        #pragma unroll
        for (int k = 0; k < 3; ++k) {
            const float* cb = &xs[(k * 64 + l) * 20];
            #pragma unroll
            for (int g = 0; g < 4; ++g) {
                float4 v = *(const float4*)&cb[4 * g];
                acc[g][0].x += v.x; acc[g][0].y += v.y;
                acc[g][1].x += v.z; acc[g][1].y += v.w;
            }
        }
        float vsum = 0.f;
        #pragma unroll
        for (int g = 0; g < 4; ++g) {
            float m0 = fmaxf(LRELU(acc[g][0].x), LRELU(acc[g][0].y));
            float m1 = fmaxf(LRELU(acc[g][1].x), LRELU(acc[g][1].y));
            float pm0 = fmaxf(m0, __shfl_xor(m0, 4));
            float pm1 = fmaxf(m1, __shfl_xor(m1, 4));
            float contrib = ((r & 1) == 0) ? (pm0 + pm1) : 0.f;
            vsum += contrib * wc[c0 + g];
        }
        #pragma unroll
        for (int off = 32; off > 0; off >>= 1) vsum += __shfl_xor(vsum, off);
        if (l == 0) {
            float o = vsum * (1.f / 64.f);
            if (cog == 0) o += bc[0];
            atomicAdd(&out[b], o);
        }
    }
}

extern "C" void kernel_launch(void* const* d_in, const int* in_sizes, int n_in,
                              void* d_out, int out_size, void* d_ws, size_t ws_size,
                              hipStream_t stream) {
    const float* x  = (const float*)d_in[0];
    const float* w1 = (const float*)d_in[1];
    const float* b1 = (const float*)d_in[2];
    const float* w2 = (const float*)d_in[3];
    const float* b2 = (const float*)d_in[4];
    const float* w3 = (const float*)d_in[5];
    const float* b3 = (const float*)d_in[6];
    const float* wc = (const float*)d_in[7];
    const float* bc = (const float*)d_in[8];
    float* out = (float*)d_out;

    float* P1H = (float*)d_ws;                    // [32][32][34][36] ~5.4 MB
    float* p2H = P1H + P1H_ELEMS;                 // [32][64][18][20] ~2.8 MB

    k1<<<dim3(32, 32), 256, 0, stream>>>(x, w1, b1, P1H, out);
    k2<<<dim3(32, 32), 256, 0, stream>>>(P1H, w2, b2, p2H);
    k3<<<dim3(32, 32), 256, 0, stream>>>(p2H, w3, b3, wc, bc, out);
}